// Round 1
// baseline (93.574 us; speedup 1.0000x reference)
//
#include <hip/hip_runtime.h>

#define F_   512
#define FF_  (512 * 512)
#define C_   128

typedef __attribute__((ext_vector_type(4))) float f32x4;
typedef __attribute__((ext_vector_type(8))) short s16x8;
typedef __attribute__((ext_vector_type(4))) unsigned short u16x4;

__device__ __forceinline__ unsigned short f2bf(float f) {
    union { float f; unsigned u; } v; v.f = f;
    unsigned r = v.u + 0x7fffu + ((v.u >> 16) & 1u);   // RNE
    return (unsigned short)(r >> 16);
}

__device__ __forceinline__ s16x8 pack8(f32x4 lo, f32x4 hi) {
    s16x8 r;
    r[0] = (short)f2bf(lo[0]); r[1] = (short)f2bf(lo[1]);
    r[2] = (short)f2bf(lo[2]); r[3] = (short)f2bf(lo[3]);
    r[4] = (short)f2bf(hi[0]); r[5] = (short)f2bf(hi[1]);
    r[6] = (short)f2bf(hi[2]); r[7] = (short)f2bf(hi[3]);
    return r;
}

#define GLDS16(gp, lp)                                                         \
    __builtin_amdgcn_global_load_lds(                                          \
        (const __attribute__((address_space(1))) void*)(gp),                   \
        (__attribute__((address_space(3))) void*)(lp), 16, 0, 0)

// ---------------------------------------------------------------------------
// Kernel 1: params = phi @ Wc^T (+bc), mask, write wT[b][k][i] bf16 + bias fp32.
// Blocks 0..1023: w part. Tile = 32 i x 8 k (MFMA N-tile = 2i x 8k cols).
// Blocks 1024..1151: bias part (p in [FF, FF+F)), fp32 VALU.
// ---------------------------------------------------------------------------
__global__ __launch_bounds__(256) void k1_params(
    const float* __restrict__ phi, const float* __restrict__ Wc,
    const float* __restrict__ bc, unsigned short* __restrict__ wT,
    float* __restrict__ biasWS)
{
    const int blk = blockIdx.x;
    const int tid = threadIdx.x;

    if (blk >= 1024) {                      // ---- bias part ----
        int g = ((blk - 1024) << 8) + tid;  // 0..32767
        int k = g >> 6, b = g & 63;         // 64 lanes share one Wc row (broadcast)
        const f32x4* w4 = (const f32x4*)(Wc + (size_t)(FF_ + k) * C_);
        const f32x4* p4 = (const f32x4*)(phi + b * C_);
        float acc = bc[FF_ + k];
#pragma unroll
        for (int c = 0; c < 32; ++c) {
            f32x4 a = w4[c], q = p4[c];
            acc += a[0]*q[0] + a[1]*q[1] + a[2]*q[2] + a[3]*q[3];
        }
        biasWS[(b << 9) + k] = acc;
        return;
    }

    // LDS transpose buffer: [b][kq][ii] ; b-stride 656 B (328 us), k-stride 80 B (40 us)
    __shared__ unsigned short trans[64 * 328];   // 41.98 KB

    const int lane = tid & 63, wave = tid >> 6;
    const int i0 = (blk >> 6) * 32;              // 16 i-tiles
    const int k0 = (blk & 63) * 8;               // 64 k-tiles

    // Hoist phi A-fragments: a[mt][kk]; A row = b-local = lane&15, K elems c = kk*32+(lane>>4)*8+j
    s16x8 afr[4][4];
    {
        const int brow = lane & 15;
        const int cb   = (lane >> 4) << 3;
#pragma unroll
        for (int mt = 0; mt < 4; ++mt)
#pragma unroll
            for (int kk = 0; kk < 4; ++kk) {
                const float* p = phi + (mt * 16 + brow) * C_ + kk * 32 + cb;
                afr[mt][kk] = pack8(*(const f32x4*)p, *(const f32x4*)(p + 4));
            }
    }

    const int col  = lane & 15;        // MFMA N-col: maps to (di, kq)
    const int di   = col >> 3;
    const int kq   = col & 7;
    const int kcur = k0 + kq;
    const int cb   = (lane >> 4) << 3;
    const int km   = kcur % 63;

#pragma unroll
    for (int t = 0; t < 4; ++t) {
        const int ibase = i0 + ((wave << 2) + t) * 2;
        const int icur  = ibase + di;
        const float* wrow = Wc + ((size_t)icur * F_ + kcur) * C_ + cb;

        s16x8 bfr[4];
#pragma unroll
        for (int kk = 0; kk < 4; ++kk)
            bfr[kk] = pack8(*(const f32x4*)(wrow + kk * 32),
                            *(const f32x4*)(wrow + kk * 32 + 4));

        f32x4 acc[4];
#pragma unroll
        for (int mt = 0; mt < 4; ++mt) acc[mt] = (f32x4){0.f, 0.f, 0.f, 0.f};
#pragma unroll
        for (int kk = 0; kk < 4; ++kk)
#pragma unroll
            for (int mt = 0; mt < 4; ++mt)
                acc[mt] = __builtin_amdgcn_mfma_f32_16x16x32_bf16(
                    afr[mt][kk], bfr[kk], acc[mt], 0, 0, 0);

        const float bcv  = bc[icur * F_ + kcur];
        const bool  keep = (icur % 63) >= km;     // mask: d[i] >= d[k]
        const int   ii   = icur - i0;
#pragma unroll
        for (int mt = 0; mt < 4; ++mt)
#pragma unroll
            for (int r = 0; r < 4; ++r) {
                int b = mt * 16 + ((lane >> 4) << 2) + r;   // D row = (lane>>4)*4+reg
                unsigned short hv = keep ? f2bf(acc[mt][r] + bcv) : (unsigned short)0;
                trans[b * 328 + kq * 40 + ii] = hv;
            }
    }
    __syncthreads();

    // Store phase: 512 (b,kk) pairs, 64 B of i each, coalesced 16B stores.
#pragma unroll
    for (int j = 0; j < 2; ++j) {
        int q = (j << 8) + tid;
        int b = q >> 3, kk = q & 7;
        const s16x8* s = (const s16x8*)&trans[b * 328 + kk * 40];
        unsigned short* d = wT + (((size_t)((b << 9) + k0 + kk)) << 9) + i0;
#pragma unroll
        for (int c = 0; c < 4; ++c) ((s16x8*)d)[c] = s[c];
    }
}

// ---------------------------------------------------------------------------
// Kernel 2: per (b, 64-row tile): t=relu(X)@mw+bias; t=relu(t)@mw+bias; out=X+t
// 8 waves (2 n x 4 k). A in LDS [64][520] bf16 (pad kills bank conflicts).
// B (wT) streamed via global_load_lds into double-buffered 32KB chunks,
// XOR-swizzled (slot ^= (k>>1)&3) on both the global source and the read.
// ---------------------------------------------------------------------------
#define SMEM_BOFF 66560           // 64*1040
#define CHUNK_B   32768
#define SMEM_TOT  (66560 + 2 * 32768)   // 132096

__global__ __launch_bounds__(512) void k2_apply(
    const float* __restrict__ X, const unsigned short* __restrict__ wT,
    const float* __restrict__ biasWS, float* __restrict__ out)
{
    extern __shared__ char smem[];
    unsigned short* A_lds = (unsigned short*)smem;

    const int blk = blockIdx.x;
    const int sw  = ((blk & 7) << 5) + (blk >> 3);   // XCD swizzle: b's 4 blocks co-XCD
    const int b   = sw >> 2;
    const int n0  = (sw & 3) << 6;

    const int tid = threadIdx.x, lane = tid & 63, wave = tid >> 6;
    const int wn = wave >> 2, wk = wave & 3;

    const float* Xb = X + (((size_t)(b * 256 + n0)) << 9);
    float*       Ob = out + (((size_t)(b * 256 + n0)) << 9);
    const unsigned short* wTb = wT + ((size_t)b << 18);

    float biasr[8];
#pragma unroll
    for (int nt = 0; nt < 8; ++nt)
        biasr[nt] = biasWS[(b << 9) + (wk << 7) + (nt << 4) + (lane & 15)];

    // stage relu(X) -> A_lds bf16
    {
        const f32x4* X4 = (const f32x4*)Xb;
#pragma unroll
        for (int j = 0; j < 16; ++j) {
            int f = (j << 9) + tid;            // float4 index, 64 rows x 128
            int row = f >> 7, c4 = f & 127;
            f32x4 v = X4[f];
            u16x4 h;
#pragma unroll
            for (int e = 0; e < 4; ++e) h[e] = f2bf(fmaxf(v[e], 0.f));
            *(u16x4*)&A_lds[row * 520 + (c4 << 2)] = h;
        }
    }

    const int srcslot = ((lane & 3) ^ ((lane >> 3) & 3)) << 3;  // elem offset for glds source

    f32x4 acc[2][8];

    for (int phase = 0; phase < 2; ++phase) {
#pragma unroll
        for (int mt = 0; mt < 2; ++mt)
#pragma unroll
            for (int nt = 0; nt < 8; ++nt) acc[mt][nt] = (f32x4){0.f, 0.f, 0.f, 0.f};

        // prologue: stage chunk 0 into buf 0
#pragma unroll
        for (int g = 0; g < 4; ++g) {
            int krow = (wave << 6) + (g << 4) + (lane >> 2);
            const unsigned short* src = wTb + ((size_t)krow << 9) + srcslot;
            char* lp = smem + SMEM_BOFF + (((wave << 6) + (g << 4)) << 6);
            GLDS16(src, lp);
        }
        asm volatile("s_waitcnt vmcnt(0)" ::: "memory");
        __syncthreads();   // also covers A_lds writes (phase-0 stage / transition)

        for (int c = 0; c < 16; ++c) {
            const int cur = c & 1;
            if (c < 15) {
                const int i0n = (c + 1) << 5;
#pragma unroll
                for (int g = 0; g < 4; ++g) {
                    int krow = (wave << 6) + (g << 4) + (lane >> 2);
                    const unsigned short* src = wTb + ((size_t)krow << 9) + i0n + srcslot;
                    char* lp = smem + SMEM_BOFF + (cur ^ 1) * CHUNK_B
                             + (((wave << 6) + (g << 4)) << 6);
                    GLDS16(src, lp);
                }
            }
            const int i0c = c << 5;
            s16x8 afr[2];
#pragma unroll
            for (int mt = 0; mt < 2; ++mt) {
                int n = (wn << 5) + (mt << 4) + (lane & 15);
                afr[mt] = *(const s16x8*)&A_lds[n * 520 + i0c + ((lane >> 4) << 3)];
            }
            const unsigned short* Bb =
                (const unsigned short*)(smem + SMEM_BOFF + cur * CHUNK_B);
#pragma unroll
            for (int nt = 0; nt < 8; ++nt) {
                int k = (wk << 7) + (nt << 4) + (lane & 15);
                int slot = (((lane >> 4) ^ ((k >> 1) & 3)) << 3);
                s16x8 bfr = *(const s16x8*)&Bb[(k << 5) + slot];
#pragma unroll
                for (int mt = 0; mt < 2; ++mt)
                    acc[mt][nt] = __builtin_amdgcn_mfma_f32_16x16x32_bf16(
                        afr[mt], bfr, acc[mt][nt], 0, 0, 0);
            }
            asm volatile("s_waitcnt vmcnt(0)" ::: "memory");
            __syncthreads();
        }

        if (phase == 0) {   // transition: A_lds <- relu(acc + bias) bf16
#pragma unroll
            for (int mt = 0; mt < 2; ++mt)
#pragma unroll
                for (int nt = 0; nt < 8; ++nt) {
                    int k = (wk << 7) + (nt << 4) + (lane & 15);
#pragma unroll
                    for (int r = 0; r < 4; ++r) {
                        int n = (wn << 5) + (mt << 4) + ((lane >> 4) << 2) + r;
                        A_lds[n * 520 + k] =
                            f2bf(fmaxf(acc[mt][nt][r] + biasr[nt], 0.f));
                    }
                }
            __syncthreads();
        }
    }

    // epilogue: out = X + t2 + bias
#pragma unroll
    for (int mt = 0; mt < 2; ++mt)
#pragma unroll
        for (int nt = 0; nt < 8; ++nt) {
            int k = (wk << 7) + (nt << 4) + (lane & 15);
#pragma unroll
            for (int r = 0; r < 4; ++r) {
                int n = (wn << 5) + (mt << 4) + ((lane >> 4) << 2) + r;
                size_t off = ((size_t)n << 9) + k;
                Ob[off] = Xb[off] + acc[mt][nt][r] + biasr[nt];
            }
        }
}

extern "C" void kernel_launch(void* const* d_in, const int* in_sizes, int n_in,
                              void* d_out, int out_size, void* d_ws, size_t ws_size,
                              hipStream_t stream) {
    const float* inputs = (const float*)d_in[0];
    const float* phi    = (const float*)d_in[1];
    const float* Wc     = (const float*)d_in[2];
    const float* bc     = (const float*)d_in[3];
    float* out = (float*)d_out;

    unsigned short* wT = (unsigned short*)d_ws;                       // 64*512*512 bf16 = 32 MiB
    float* biasWS = (float*)((char*)d_ws + (size_t)64 * 512 * 512 * 2); // 64*512 fp32

    hipLaunchKernelGGL(k1_params, dim3(1152), dim3(256), 0, stream,
                       phi, Wc, bc, wT, biasWS);

    hipFuncSetAttribute((const void*)k2_apply,
                        hipFuncAttributeMaxDynamicSharedMemorySize, SMEM_TOT);
    hipLaunchKernelGGL(k2_apply, dim3(256), dim3(512), SMEM_TOT, stream,
                       inputs, wT, biasWS, out);
}

// Round 2
// 73.137 us; speedup vs baseline: 1.2794x; 1.2794x over previous
//
#include <hip/hip_runtime.h>

#define F_   512
#define FF_  (512 * 512)
#define C_   128

typedef __attribute__((ext_vector_type(4))) float f32x4;
typedef __attribute__((ext_vector_type(8))) short s16x8;
typedef __attribute__((ext_vector_type(4))) unsigned short u16x4;

__device__ __forceinline__ unsigned short f2bf(float f) {
    union { float f; unsigned u; } v; v.f = f;
    unsigned r = v.u + 0x7fffu + ((v.u >> 16) & 1u);   // RNE
    return (unsigned short)(r >> 16);
}

__device__ __forceinline__ s16x8 pack8(f32x4 lo, f32x4 hi) {
    s16x8 r;
    r[0] = (short)f2bf(lo[0]); r[1] = (short)f2bf(lo[1]);
    r[2] = (short)f2bf(lo[2]); r[3] = (short)f2bf(lo[3]);
    r[4] = (short)f2bf(hi[0]); r[5] = (short)f2bf(hi[1]);
    r[6] = (short)f2bf(hi[2]); r[7] = (short)f2bf(hi[3]);
    return r;
}

#define GLDS16(gp, lp)                                                         \
    __builtin_amdgcn_global_load_lds(                                          \
        (const __attribute__((address_space(1))) void*)(gp),                   \
        (__attribute__((address_space(3))) void*)(lp), 16, 0, 0)

// ---------------------------------------------------------------------------
// Kernel 1 v2: params = phi @ Wc^T (+bc), mask, -> wT[b][k][i] bf16 + bias.
// Blocks 0..2047: tile 16i x 8k. Per col-tile (2i x 8k = 16 Wc rows), all 4
// waves share one global_load_lds-staged chunk (dbuf, counted vmcnt(2));
// each wave owns one 16-b m-tile (phi frags = 16 VGPR). Fully-masked
// col-tiles skip the Wc read entirely (trans pre-zeroed).
// Blocks 2048..2175: bias rows (p in [FF, FF+F)), fp32 VALU broadcast.
// ---------------------------------------------------------------------------
__global__ __launch_bounds__(256, 4) void k1_params(
    const float* __restrict__ phi, const float* __restrict__ Wc,
    const float* __restrict__ bc, unsigned short* __restrict__ wT,
    float* __restrict__ biasWS)
{
    const int blk = blockIdx.x;
    const int tid = threadIdx.x;

    if (blk >= 2048) {                      // ---- bias part ----
        int g = ((blk - 2048) << 8) + tid;  // 0..32767
        int k = g >> 6, b = g & 63;         // 64 lanes share one Wc row
        const f32x4* w4 = (const f32x4*)(Wc + (size_t)(FF_ + k) * C_);
        const f32x4* p4 = (const f32x4*)(phi + b * C_);
        float acc = bc[FF_ + k];
#pragma unroll
        for (int c = 0; c < 32; ++c) {
            f32x4 a = w4[c], q = p4[c];
            acc += a[0]*q[0] + a[1]*q[1] + a[2]*q[2] + a[3]*q[3];
        }
        biasWS[(b << 9) + k] = acc;
        return;
    }

    __shared__ __align__(16) float stg[2][2048];            // 2 x 8 KB
    __shared__ __align__(16) unsigned short trans[64 * 136]; // 17.4 KB, pad 136

    const int lane = tid & 63, wave = tid >> 6;
    const int i0 = (blk >> 6) << 4;     // 32 i-tiles of 16
    const int k0 = (blk & 63) << 3;     // 64 k-tiles of 8

    // zero trans (1088 x 16B chunks / 256 threads)
    {
        s16x8 z = {0,0,0,0,0,0,0,0};
#pragma unroll
        for (int j = 0; j < 5; ++j) {
            int idx = (j << 8) + tid;
            if (idx < 1088) *(s16x8*)&trans[idx * 8] = z;
        }
    }

    // skip mask: col-tile ct fully masked iff max(d_i) < min(d_k)
    unsigned skipm = 0;
    {
        int kmin = 63;
#pragma unroll
        for (int kk = 0; kk < 8; ++kk) { int dk = (k0 + kk) % 63; kmin = dk < kmin ? dk : kmin; }
#pragma unroll
        for (int ct = 0; ct < 8; ++ct) {
            int a  = (i0 + 2 * ct) % 63;
            int b2 = (i0 + 2 * ct + 1) % 63;
            int imax = a > b2 ? a : b2;
            if (imax < kmin) skipm |= 1u << ct;
        }
    }

    // hoist phi A-frags for this wave's 16-b m-tile (16 VGPRs)
    const int quad = lane >> 4;
    s16x8 afr[4];
    {
        const int brow = (wave << 4) + (lane & 15);
        const int cb   = quad << 3;
#pragma unroll
        for (int kk = 0; kk < 4; ++kk) {
            const float* p = phi + brow * C_ + kk * 32 + cb;
            afr[kk] = pack8(*(const f32x4*)p, *(const f32x4*)(p + 4));
        }
    }

    // per-lane output coords (D col = lane&15 -> (di,kq))
    const int c16 = lane & 15;
    const int di  = c16 >> 3, kq = c16 & 7;
    const int kcur = k0 + kq;
    const int dk   = kcur % 63;

    // hoist bc values per col-tile
    float bcv[8];
#pragma unroll
    for (int ct = 0; ct < 8; ++ct)
        bcv[ct] = bc[(i0 + ct * 2 + di) * F_ + kcur];

    // staging geometry: per 4KB span, lane -> row rl8 = wave*2 + lane>>5,
    // 16B slot s16 = lane&31; source pre-swizzled at 32B granularity.
    const int rl8   = (wave << 1) + (lane >> 5);
    const int s16   = lane & 31;
    const int sb32  = (s16 >> 1) ^ rl8;
    const int shalf = s16 & 1;

    auto STAGE = [&](int ct, int buf) {
#pragma unroll
        for (int d = 0; d < 2; ++d) {
            const float* src = Wc
                + ((size_t)((i0 + ct * 2 + d) * F_ + k0 + rl8)) * C_
                + sb32 * 8 + shalf * 4;
            GLDS16(src, (char*)&stg[buf][(d << 10) + (wave << 8)]);
        }
    };

    bool curst = !(skipm & 1u);
    if (curst) STAGE(0, 0);

    for (int ct = 0; ct < 8; ++ct) {
        const int  bufA   = ct & 1;
        const bool nextst = (ct < 7) && !((skipm >> (ct + 1)) & 1u);
        if (nextst) STAGE(ct + 1, bufA ^ 1);
        if (curst) {
            if (nextst) asm volatile("s_waitcnt vmcnt(2)" ::: "memory");
            else        asm volatile("s_waitcnt vmcnt(0)" ::: "memory");
        }
        __builtin_amdgcn_s_barrier();
        if (curst) {
            f32x4 acc = (f32x4){0.f, 0.f, 0.f, 0.f};
            const float* sb = stg[bufA];
#pragma unroll
            for (int kk = 0; kk < 4; ++kk) {
                int off = c16 * 128 + ((((kk << 2) + quad) ^ kq) << 3);
                s16x8 bfr = pack8(*(const f32x4*)&sb[off],
                                  *(const f32x4*)&sb[off + 4]);
                acc = __builtin_amdgcn_mfma_f32_16x16x32_bf16(
                    afr[kk], bfr, acc, 0, 0, 0);
            }
            const int  icur = i0 + ct * 2 + di;
            const bool keep = (icur % 63) >= dk;
            const int  ii   = ct * 2 + di;
            const float bv  = bcv[ct];
#pragma unroll
            for (int r = 0; r < 4; ++r) {
                int b = (wave << 4) + (quad << 2) + r;
                unsigned short hv = keep ? f2bf(acc[r] + bv) : (unsigned short)0;
                trans[b * 136 + (kq << 4) + ii] = hv;
            }
        }
        __builtin_amdgcn_s_barrier();
        curst = nextst;
    }
    __syncthreads();

    // store: 64 b x 8 k x 16 i bf16 -> wT, 16B chunks
#pragma unroll
    for (int j = 0; j < 4; ++j) {
        int q = (j << 8) + tid;            // 0..1023
        int b = q >> 4, kq2 = (q >> 1) & 7, h = q & 1;
        s16x8 v = *(const s16x8*)&trans[b * 136 + (kq2 << 4) + (h << 3)];
        *(s16x8*)&wT[(((size_t)((b << 9) + k0 + kq2)) << 9) + i0 + (h << 3)] = v;
    }
}

// ---------------------------------------------------------------------------
// Kernel 2 (unchanged): per (b, 64-row tile): two chained GEMMs vs wT + bias,
// residual epilogue. Already ~at BW floor (~15 us).
// ---------------------------------------------------------------------------
#define SMEM_BOFF 66560           // 64*1040
#define CHUNK_B   32768
#define SMEM_TOT  (66560 + 2 * 32768)   // 132096

__global__ __launch_bounds__(512) void k2_apply(
    const float* __restrict__ X, const unsigned short* __restrict__ wT,
    const float* __restrict__ biasWS, float* __restrict__ out)
{
    extern __shared__ char smem[];
    unsigned short* A_lds = (unsigned short*)smem;

    const int blk = blockIdx.x;
    const int sw  = ((blk & 7) << 5) + (blk >> 3);   // XCD swizzle
    const int b   = sw >> 2;
    const int n0  = (sw & 3) << 6;

    const int tid = threadIdx.x, lane = tid & 63, wave = tid >> 6;
    const int wn = wave >> 2, wk = wave & 3;

    const float* Xb = X + (((size_t)(b * 256 + n0)) << 9);
    float*       Ob = out + (((size_t)(b * 256 + n0)) << 9);
    const unsigned short* wTb = wT + ((size_t)b << 18);

    float biasr[8];
#pragma unroll
    for (int nt = 0; nt < 8; ++nt)
        biasr[nt] = biasWS[(b << 9) + (wk << 7) + (nt << 4) + (lane & 15)];

    // stage relu(X) -> A_lds bf16
    {
        const f32x4* X4 = (const f32x4*)Xb;
#pragma unroll
        for (int j = 0; j < 16; ++j) {
            int f = (j << 9) + tid;
            int row = f >> 7, c4 = f & 127;
            f32x4 v = X4[f];
            u16x4 h;
#pragma unroll
            for (int e = 0; e < 4; ++e) h[e] = f2bf(fmaxf(v[e], 0.f));
            *(u16x4*)&A_lds[row * 520 + (c4 << 2)] = h;
        }
    }

    const int srcslot = ((lane & 3) ^ ((lane >> 3) & 3)) << 3;

    f32x4 acc[2][8];

    for (int phase = 0; phase < 2; ++phase) {
#pragma unroll
        for (int mt = 0; mt < 2; ++mt)
#pragma unroll
            for (int nt = 0; nt < 8; ++nt) acc[mt][nt] = (f32x4){0.f, 0.f, 0.f, 0.f};

#pragma unroll
        for (int g = 0; g < 4; ++g) {
            int krow = (wave << 6) + (g << 4) + (lane >> 2);
            const unsigned short* src = wTb + ((size_t)krow << 9) + srcslot;
            char* lp = smem + SMEM_BOFF + (((wave << 6) + (g << 4)) << 6);
            GLDS16(src, lp);
        }
        asm volatile("s_waitcnt vmcnt(0)" ::: "memory");
        __syncthreads();

        for (int c = 0; c < 16; ++c) {
            const int cur = c & 1;
            if (c < 15) {
                const int i0n = (c + 1) << 5;
#pragma unroll
                for (int g = 0; g < 4; ++g) {
                    int krow = (wave << 6) + (g << 4) + (lane >> 2);
                    const unsigned short* src = wTb + ((size_t)krow << 9) + i0n + srcslot;
                    char* lp = smem + SMEM_BOFF + (cur ^ 1) * CHUNK_B
                             + (((wave << 6) + (g << 4)) << 6);
                    GLDS16(src, lp);
                }
            }
            const int i0c = c << 5;
            s16x8 afr[2];
#pragma unroll
            for (int mt = 0; mt < 2; ++mt) {
                int n = (wn << 5) + (mt << 4) + (lane & 15);
                afr[mt] = *(const s16x8*)&A_lds[n * 520 + i0c + ((lane >> 4) << 3)];
            }
            const unsigned short* Bb =
                (const unsigned short*)(smem + SMEM_BOFF + cur * CHUNK_B);
#pragma unroll
            for (int nt = 0; nt < 8; ++nt) {
                int k = (wk << 7) + (nt << 4) + (lane & 15);
                int slot = (((lane >> 4) ^ ((k >> 1) & 3)) << 3);
                s16x8 bfr = *(const s16x8*)&Bb[(k << 5) + slot];
#pragma unroll
                for (int mt = 0; mt < 2; ++mt)
                    acc[mt][nt] = __builtin_amdgcn_mfma_f32_16x16x32_bf16(
                        afr[mt], bfr, acc[mt][nt], 0, 0, 0);
            }
            asm volatile("s_waitcnt vmcnt(0)" ::: "memory");
            __syncthreads();
        }

        if (phase == 0) {
#pragma unroll
            for (int mt = 0; mt < 2; ++mt)
#pragma unroll
                for (int nt = 0; nt < 8; ++nt) {
                    int k = (wk << 7) + (nt << 4) + (lane & 15);
#pragma unroll
                    for (int r = 0; r < 4; ++r) {
                        int n = (wn << 5) + (mt << 4) + ((lane >> 4) << 2) + r;
                        A_lds[n * 520 + k] =
                            f2bf(fmaxf(acc[mt][nt][r] + biasr[nt], 0.f));
                    }
                }
            __syncthreads();
        }
    }

#pragma unroll
    for (int mt = 0; mt < 2; ++mt)
#pragma unroll
        for (int nt = 0; nt < 8; ++nt) {
            int k = (wk << 7) + (nt << 4) + (lane & 15);
#pragma unroll
            for (int r = 0; r < 4; ++r) {
                int n = (wn << 5) + (mt << 4) + ((lane >> 4) << 2) + r;
                size_t off = ((size_t)n << 9) + k;
                Ob[off] = Xb[off] + acc[mt][nt][r] + biasr[nt];
            }
        }
}

extern "C" void kernel_launch(void* const* d_in, const int* in_sizes, int n_in,
                              void* d_out, int out_size, void* d_ws, size_t ws_size,
                              hipStream_t stream) {
    const float* inputs = (const float*)d_in[0];
    const float* phi    = (const float*)d_in[1];
    const float* Wc     = (const float*)d_in[2];
    const float* bc     = (const float*)d_in[3];
    float* out = (float*)d_out;

    unsigned short* wT = (unsigned short*)d_ws;                         // 32 MiB
    float* biasWS = (float*)((char*)d_ws + (size_t)64 * 512 * 512 * 2); // 64*512 fp32

    hipLaunchKernelGGL(k1_params, dim3(2176), dim3(256), 0, stream,
                       phi, Wc, bc, wT, biasWS);

    hipFuncSetAttribute((const void*)k2_apply,
                        hipFuncAttributeMaxDynamicSharedMemorySize, SMEM_TOT);
    hipLaunchKernelGGL(k2_apply, dim3(256), dim3(512), SMEM_TOT, stream,
                       inputs, wT, biasWS, out);
}